// Round 13
// baseline (307.490 us; speedup 1.0000x reference)
//
#include <hip/hip_runtime.h>
#include <hip/hip_fp16.h>
#include <math.h>

// Problem constants (from setup_inputs)
#define NN   50000          // nodes
#define EE   800000         // edges (without self loops)
#define ETOT 850000         // edges + self loops
#define INF_FEATS 22
#define D1   256            // HEADS*HID
#define NH   4
#define D2   32
#define BN_EPS 1e-5f
#define NEG_SLOPE 0.2f
#define SCAN_B 49
#define AB_ROWS 8
#define AB_BLOCKS (NN / AB_ROWS)           // 6250 exact
#define CNT_BLOCKS ((ETOT + 255) / 256)

typedef _Float16 f16x8 __attribute__((ext_vector_type(8)));
typedef float f32x4 __attribute__((ext_vector_type(4)));

__device__ __forceinline__ float2 h2f(unsigned u) {
    __half2 h = *reinterpret_cast<__half2*>(&u);
    return __half22float2(h);
}

// ---------------------------------------------------------------------------
// prep2: zero cnt (all blocks) + zero scan flags + WA matrices (block 0).
// WA[k,h] = sum_c W1[k, h*64+c] * att[h,c]  (22x4, for src and dst).
__global__ __launch_bounds__(1024) void prep2(const float* __restrict__ W1,
                                              const float* __restrict__ atts,
                                              const float* __restrict__ attd,
                                              float* __restrict__ WAs,
                                              float* __restrict__ WAd,
                                              int* __restrict__ cnt,
                                              int* __restrict__ flags) {
    const int i = blockIdx.x * 1024 + threadIdx.x;
    if (i < NN) cnt[i] = 0;
    if (blockIdx.x == 0) {
        const int t = threadIdx.x;
        if (t < SCAN_B) flags[t] = 0;
        if (t >= 128 && t < 128 + INF_FEATS * NH) {
            const int k = (t - 128) >> 2, h = (t - 128) & 3;
            float s = 0.f, d = 0.f;
            for (int c = 0; c < 64; ++c) {
                const float w = W1[k * D1 + h * 64 + c];
                s = fmaf(w, atts[h * 64 + c], s);
                d = fmaf(w, attd[h * 64 + c], d);
            }
            WAs[k * NH + h] = s;
            WAd[k * NH + h] = d;
        }
    }
}

// ---------------------------------------------------------------------------
// sAB_count: blocks [0,AB_BLOCKS): h1 = x@W1 (fp16, 8 rows/block, x in LDS)
//            + as1/ad1 via the precomputed 22x4 WA matrices.
//            blocks [AB_BLOCKS, ..): edge-parallel degree count + rank store.
__global__ __launch_bounds__(256) void sAB_count(
    const float* __restrict__ x, const float* __restrict__ W1,
    const float* __restrict__ WAs, const float* __restrict__ WAd,
    const int* __restrict__ ei, __half* __restrict__ h1h,
    float* __restrict__ as1, float* __restrict__ ad1,
    int* __restrict__ cnt, int* __restrict__ rank) {
    if (blockIdx.x >= AB_BLOCKS) {
        const int e = (blockIdx.x - AB_BLOCKS) * 256 + threadIdx.x;
        if (e < ETOT) {
            int dst = (e < EE) ? ei[EE + e] : (e - EE);
            rank[e] = atomicAdd(&cnt[dst], 1);   // position within dst bucket
        }
        return;
    }
    __shared__ float xs[AB_ROWS][INF_FEATS];
    const int t = threadIdx.x;
    const int n0 = blockIdx.x * AB_ROWS;
    for (int i = t; i < AB_ROWS * INF_FEATS; i += 256)
        xs[i / INF_FEATS][i % INF_FEATS] = x[n0 * INF_FEATS + i];
    __syncthreads();
    float acc[AB_ROWS];
#pragma unroll
    for (int r = 0; r < AB_ROWS; ++r) acc[r] = 0.f;
#pragma unroll
    for (int k = 0; k < INF_FEATS; ++k) {
        const float wv = W1[k * D1 + t];
#pragma unroll
        for (int r = 0; r < AB_ROWS; ++r) acc[r] = fmaf(xs[r][k], wv, acc[r]);
    }
#pragma unroll
    for (int r = 0; r < AB_ROWS; ++r)
        h1h[(size_t)(n0 + r) * D1 + t] = __float2half(acc[r]);
    // attention dots: 64 threads, each one (row, head, src/dst) triple
    if (t < AB_ROWS * NH * 2) {
        const int r = t >> 3, idx = t & 7, h = idx >> 1;
        const float* WA = (idx & 1) ? WAd : WAs;
        float a = 0.f;
#pragma unroll
        for (int k = 0; k < INF_FEATS; ++k)
            a = fmaf(xs[r][k], WA[k * NH + h], a);
        ((idx & 1) ? ad1 : as1)[(n0 + r) * NH + h] = a;
    }
}

// ---------------------------------------------------------------------------
// scan_f: fused exclusive scan via decoupled lookback. 49 co-resident blocks.
// Publishes (blocksum+1) through device-scope atomics; flags pre-zeroed by
// prep2 each launch (atomic read avoids stale-L2 cross-XCD hazards).
__global__ __launch_bounds__(1024) void scan_f(const int* __restrict__ cnt,
                                               int* __restrict__ offs,
                                               int* __restrict__ flags) {
    __shared__ int sh[1024];
    __shared__ int sbase;
    const int b = blockIdx.x, t = threadIdx.x, i = b * 1024 + t;
    const int v = (i < NN) ? cnt[i] : 0;
    sh[t] = v;
    __syncthreads();
    for (int off = 1; off < 1024; off <<= 1) {
        int u = (t >= off) ? sh[t - off] : 0;
        __syncthreads();
        sh[t] += u;
        __syncthreads();
    }
    if (t == 1023) atomicExch(&flags[b], sh[1023] + 1);  // publish (sum+1)
    if (t == 0) {
        int base = 0;
        for (int j = 0; j < b; ++j) {
            int f;
            while ((f = atomicAdd(&flags[j], 0)) == 0) { }
            base += f - 1;
        }
        sbase = base;
    }
    __syncthreads();
    if (i < NN) offs[i] = sbase + sh[t] - v;   // global exclusive
    if (i == 0) offs[NN] = ETOT;
}

// c_scatter2: atomic-free scatter using precomputed ranks
__global__ void c_scatter2(const int* __restrict__ ei,
                           const int* __restrict__ offs,
                           const int* __restrict__ rank,
                           int* __restrict__ ssrc) {
    int e = blockIdx.x * blockDim.x + threadIdx.x;
    if (e >= ETOT) return;
    int src, dst;
    if (e < EE) { src = ei[e]; dst = ei[EE + e]; }
    else        { src = dst = e - EE; }
    ssrc[offs[dst] + rank[e]] = src;
}

// ---------------------------------------------------------------------------
// g1k: layer-1 gather. One wave per node (4 nodes/block). Lane = 4 channels
// (uint2 = half4 load). Unroll x8; __launch_bounds__(256,4) raises the VGPR
// ceiling to 128 so all 8 row-gathers stay in flight (was serialized at 32).
__global__ __launch_bounds__(256, 4) void g1k(
    const uint2* __restrict__ h1q, const float* __restrict__ as1,
    const float* __restrict__ ad1, const int* __restrict__ offs,
    const int* __restrict__ ssrc, const float* __restrict__ b1,
    const float* __restrict__ g1, const float* __restrict__ be1,
    const float* __restrict__ mu1, const float* __restrict__ va1,
    uint2* __restrict__ hposth) {
    const int wv = threadIdx.x >> 6, lane = threadIdx.x & 63;
    const int n = blockIdx.x * 4 + wv;       // grid exact: 12500*4
    const int off = offs[n];
    const int deg = offs[n + 1] - off;       // >= 1 (self loop)
    const int h = lane >> 4;                 // head = (lane*4)>>6
    const float adst = ad1[n * NH + h];
    float a0 = 0.f, a1 = 0.f, a2 = 0.f, a3 = 0.f, ssum = 0.f;
    for (int p = 0; p < deg; p += 8) {
        int sj[8];
#pragma unroll
        for (int u = 0; u < 8; ++u)
            sj[u] = (p + u < deg) ? ssrc[off + p + u] : ssrc[off];
        uint2 hv[8];
#pragma unroll
        for (int u = 0; u < 8; ++u)
            hv[u] = h1q[(size_t)sj[u] * 64 + lane];
        float al[8];
#pragma unroll
        for (int u = 0; u < 8; ++u) {
            float a = as1[sj[u] * NH + h] + adst;
            a = (a >= 0.f) ? a : NEG_SLOPE * a;
            al[u] = (p + u < deg) ? __expf(a) : 0.f;
        }
#pragma unroll
        for (int u = 0; u < 8; ++u) {
            ssum += al[u];
            const float2 f0 = h2f(hv[u].x), f1 = h2f(hv[u].y);
            a0 = fmaf(al[u], f0.x, a0);
            a1 = fmaf(al[u], f0.y, a1);
            a2 = fmaf(al[u], f1.x, a2);
            a3 = fmaf(al[u], f1.y, a3);
        }
    }
    const float inv = 1.f / (ssum + 1e-16f);
    const float4 bb = ((const float4*)b1)[lane];
    const float4 mm = ((const float4*)mu1)[lane];
    const float4 vv = ((const float4*)va1)[lane];
    const float4 gg = ((const float4*)g1)[lane];
    const float4 ee = ((const float4*)be1)[lane];
    float4 o;
    o.x = (a0 * inv + bb.x - mm.x) * rsqrtf(vv.x + BN_EPS) * gg.x + ee.x;
    o.y = (a1 * inv + bb.y - mm.y) * rsqrtf(vv.y + BN_EPS) * gg.y + ee.y;
    o.z = (a2 * inv + bb.z - mm.z) * rsqrtf(vv.z + BN_EPS) * gg.z + ee.z;
    o.w = (a3 * inv + bb.w - mm.w) * rsqrtf(vv.w + BN_EPS) * gg.w + ee.w;
    o.x = (o.x > 0.f) ? o.x : expm1f(o.x);
    o.y = (o.y > 0.f) ? o.y : expm1f(o.y);
    o.z = (o.z > 0.f) ? o.z : expm1f(o.z);
    o.w = (o.w > 0.f) ? o.w : expm1f(o.w);
    __half2 p01 = __floats2half2_rn(o.x, o.y);
    __half2 p23 = __floats2half2_rn(o.z, o.w);
    uint2 st;
    st.x = *reinterpret_cast<unsigned*>(&p01);
    st.y = *reinterpret_cast<unsigned*>(&p23);
    hposth[(size_t)n * 64 + lane] = st;
}

// ---------------------------------------------------------------------------
// sFGm: h2 = hpost(fp16) @ W2 via MFMA 16x16x32_f16, fused layer-2 dots.
// Block = 4 waves x 16 rows = 64 rows; each wave: 16x32 strip, K=256.
// A layout: row=lane&15, k=(lane>>4)*8+j. B layout: col=lane&15, same k.
// C/D layout: col=lane&15, row=(lane>>4)*4+i  [m89-verified].
__global__ __launch_bounds__(256) void sFGm(
    const uint4* __restrict__ hq,          // hposth as uint4; row stride 32
    const float* __restrict__ W2,
    const float* __restrict__ atts, const float* __restrict__ attd,
    __half* __restrict__ h2h, float* __restrict__ as2, float* __restrict__ ad2) {
    const int w = threadIdx.x >> 6, l = threadIdx.x & 63;
    const int row0 = blockIdx.x * 64 + w * 16;
    const int lmod = l & 15, ldiv = l >> 4;
    f16x8 b0[8], b1[8];
#pragma unroll
    for (int ks = 0; ks < 8; ++ks) {
#pragma unroll
        for (int j = 0; j < 8; ++j) {
            const int k = ks * 32 + ldiv * 8 + j;
            b0[ks][j] = (_Float16)W2[k * D2 + lmod];
            b1[ks][j] = (_Float16)W2[k * D2 + lmod + 16];
        }
    }
    f32x4 acc0 = {0.f, 0.f, 0.f, 0.f}, acc1 = {0.f, 0.f, 0.f, 0.f};
    const int arow = min(row0 + lmod, NN - 1);        // clamp tail rows
    const uint4* ap = hq + (size_t)arow * 32 + ldiv;  // +ks*4 per step
#pragma unroll
    for (int ks = 0; ks < 8; ++ks) {
        uint4 av = ap[ks * 4];
        f16x8 a = *reinterpret_cast<f16x8*>(&av);
        acc0 = __builtin_amdgcn_mfma_f32_16x16x32_f16(a, b0[ks], acc0, 0, 0, 0);
        acc1 = __builtin_amdgcn_mfma_f32_16x16x32_f16(a, b1[ks], acc1, 0, 0, 0);
    }
    const float a2s0 = atts[lmod], a2s1 = atts[lmod + 16];
    const float a2d0 = attd[lmod], a2d1 = attd[lmod + 16];
#pragma unroll
    for (int i = 0; i < 4; ++i) {
        const int r = row0 + ldiv * 4 + i;
        const bool ok = r < NN;
        if (ok) {
            h2h[(size_t)r * D2 + lmod]      = __float2half(acc0[i]);
            h2h[(size_t)r * D2 + lmod + 16] = __float2half(acc1[i]);
        }
        float s = acc0[i] * a2s0 + acc1[i] * a2s1;
        float d = acc0[i] * a2d0 + acc1[i] * a2d1;
#pragma unroll
        for (int m = 8; m > 0; m >>= 1) {
            s += __shfl_xor(s, m);
            d += __shfl_xor(d, m);
        }
        if (ok && lmod == 0) { as2[r] = s; ad2[r] = d; }
    }
}

// ---------------------------------------------------------------------------
// g2k: layer-2 gather (fp16 h2, L2-resident). 8 nodes/block, unroll x8,
// __launch_bounds__(256,4) for deeper in-flight ILP.
__global__ __launch_bounds__(256, 4) void g2k(
    const unsigned short* __restrict__ h2u, const float* __restrict__ as2,
    const float* __restrict__ ad2, const int* __restrict__ offs,
    const int* __restrict__ ssrc, const float* __restrict__ b2,
    const float* __restrict__ g2, const float* __restrict__ be2,
    const float* __restrict__ mu2, const float* __restrict__ va2,
    float* __restrict__ out) {
    const int t = threadIdx.x;
    const int n = blockIdx.x * 8 + (t >> 5), c = t & 31;
    const int off = offs[n];
    const int deg = offs[n + 1] - off;
    const float adst = ad2[n];
    float ssum = 0.f, acc = 0.f;
    for (int p = 0; p < deg; p += 8) {
        int sj[8];
#pragma unroll
        for (int u = 0; u < 8; ++u)
            sj[u] = (p + u < deg) ? ssrc[off + p + u] : ssrc[off];
        unsigned short hv[8];
#pragma unroll
        for (int u = 0; u < 8; ++u)
            hv[u] = h2u[sj[u] * D2 + c];
        float al[8];
#pragma unroll
        for (int u = 0; u < 8; ++u) {
            float a = as2[sj[u]] + adst;
            a = (a >= 0.f) ? a : NEG_SLOPE * a;
            al[u] = (p + u < deg) ? __expf(a) : 0.f;
        }
#pragma unroll
        for (int u = 0; u < 8; ++u) {
            ssum += al[u];
            acc = fmaf(al[u], __half2float(*reinterpret_cast<__half*>(&hv[u])), acc);
        }
    }
    float v = acc / (ssum + 1e-16f) + b2[c];
    v = (v - mu2[c]) * rsqrtf(va2[c] + BN_EPS) * g2[c] + be2[c];
    v = (v > 0.f) ? v : expm1f(v);
    out[n * D2 + c] = v;
}

// ---------------------------------------------------------------------------
extern "C" void kernel_launch(void* const* d_in, const int* in_sizes, int n_in,
                              void* d_out, int out_size, void* d_ws, size_t ws_size,
                              hipStream_t stream) {
    (void)in_sizes; (void)n_in; (void)out_size; (void)ws_size;
    const float* x    = (const float*)d_in[0];
    const int*   ei   = (const int*)  d_in[1];
    const float* W1   = (const float*)d_in[2];
    const float* as1i = (const float*)d_in[3];
    const float* ad1i = (const float*)d_in[4];
    const float* b1   = (const float*)d_in[5];
    const float* W2   = (const float*)d_in[6];
    const float* as2i = (const float*)d_in[7];
    const float* ad2i = (const float*)d_in[8];
    const float* b2   = (const float*)d_in[9];
    const float* g1   = (const float*)d_in[10];
    const float* be1  = (const float*)d_in[11];
    const float* mu1  = (const float*)d_in[12];
    const float* va1  = (const float*)d_in[13];
    const float* g2   = (const float*)d_in[14];
    const float* be2  = (const float*)d_in[15];
    const float* mu2  = (const float*)d_in[16];
    const float* va2  = (const float*)d_in[17];
    float* out = (float*)d_out;

    // workspace layout (~65 MB, well under the 118.4 MB proven in Round 3)
    float* ws = (float*)d_ws;
    __half* hposth = (__half*)ws;                    // NN*256 halves (25.6 MB)
    float* as1  = ws + (size_t)NN * (D1 / 2);        // NN*4
    float* ad1  = as1 + (size_t)NN * NH;             // NN*4
    float* as2  = ad1 + (size_t)NN * NH;             // NN
    float* ad2  = as2 + NN;                          // NN
    __half* h1h = (__half*)(ad2 + NN);               // NN*256 halves (25.6 MB)
    __half* h2h = h1h + (size_t)NN * D1;             // NN*32 halves (3.2 MB)
    int* cnt   = (int*)(h2h + (size_t)NN * D2);      // NN
    int* offs  = cnt + NN;                           // NN+1
    int* rank  = offs + NN + 1;                      // ETOT
    int* ssrc  = rank + ETOT;                        // ETOT
    int* flags = ssrc + ETOT;                        // 49
    float* WAs = (float*)(flags + SCAN_B);           // 22*4
    float* WAd = WAs + INF_FEATS * NH;               // 22*4

    // zero cnt/flags + WA matrices (one kernel, replaces memset + prep)
    prep2<<<SCAN_B, 1024, 0, stream>>>(W1, as1i, ad1i, WAs, WAd, cnt, flags);
    // h1 (fp16, 8 rows/block) + attention dots via WA + degree count w/ rank
    sAB_count<<<AB_BLOCKS + CNT_BLOCKS, 256, 0, stream>>>(
        x, W1, WAs, WAd, ei, h1h, as1, ad1, cnt, rank);
    // CSR build (fused lookback scan + atomic-free scatter)
    scan_f<<<SCAN_B, 1024, 0, stream>>>(cnt, offs, flags);
    c_scatter2<<<(ETOT + 255) / 256, 256, 0, stream>>>(ei, offs, rank, ssrc);
    // layer-1 gather (softmax + aggregate + BN + ELU, fp16 out)
    g1k<<<NN / 4, 256, 0, stream>>>((const uint2*)h1h, as1, ad1, offs, ssrc,
                                    b1, g1, be1, mu1, va1, (uint2*)hposth);
    // layer 2: MFMA linear + fused dots
    sFGm<<<(NN + 63) / 64, 256, 0, stream>>>((const uint4*)hposth, W2,
                                             as2i, ad2i, h2h, as2, ad2);
    g2k<<<NN / 8, 256, 0, stream>>>((const unsigned short*)h2h, as2, ad2, offs,
                                    ssrc, b2, g2, be2, mu2, va2, out);
}